// Round 2
// baseline (252.233 us; speedup 1.0000x reference)
//
#include <hip/hip_runtime.h>

#define BB 8
#define TT_DIM 128
#define SS 512
#define DD 512
// C == D == 512

struct alignas(16) F4 { float v[4]; };

// ---------------------------------------------------------------------------
// Row-tiled GEMM, K=512: Y[n,d] = sum_k X[n,k]*W[k,d] (+bias)
// block 256 = 128 col-threads (4 cols each, full 512 d) x 2 row-halves.
// grid = N/RN. PERB: W is per-batch (context), b = n0>>7.
// ---------------------------------------------------------------------------
template<int RN, bool PERB>
__global__ __launch_bounds__(256) void gemm512(
    const float* __restrict__ X, const float* __restrict__ W,
    const float* __restrict__ bias, float* __restrict__ Y) {
  constexpr int RH = RN / 2;
  int n0 = blockIdx.x * RN;
  int tx = threadIdx.x & 127;
  int half = threadIdx.x >> 7;
  int d0 = tx * 4;
  __shared__ float xs[RN][512];
  for (int idx = threadIdx.x; idx < RN * 512; idx += 256)
    xs[idx >> 9][idx & 511] = X[(size_t)(n0 + (idx >> 9)) * 512 + (idx & 511)];
  __syncthreads();
  const float* wp = W + (PERB ? (size_t)(n0 >> 7) * SS * 512 : (size_t)0) + d0;
  float acc[RH][4] = {};
  for (int k0 = 0; k0 < 512; k0 += 4) {
    F4 w[4];
#pragma unroll
    for (int j = 0; j < 4; ++j) w[j] = *(const F4*)&wp[(size_t)(k0 + j) * 512];
#pragma unroll
    for (int r = 0; r < RH; ++r) {
      F4 xv = *(const F4*)&xs[half * RH + r][k0];
#pragma unroll
      for (int j = 0; j < 4; ++j)
#pragma unroll
        for (int c = 0; c < 4; ++c)
          acc[r][c] = fmaf(xv.v[j], w[j].v[c], acc[r][c]);
    }
  }
#pragma unroll
  for (int r = 0; r < RH; ++r) {
    F4 o;
#pragma unroll
    for (int c = 0; c < 4; ++c) o.v[c] = acc[r][c] + (bias ? bias[d0 + c] : 0.f);
    *(F4*)&Y[(size_t)(n0 + half * RH + r) * 512 + d0] = o;
  }
}

// ---------------------------------------------------------------------------
// logits[b,t,s] = sum_d tanh(mo+ma)*q + qb  =  Qsum + qb - 2*sum_d q*r
// where r = 1/(exp2(2*log2e*(mo+ma)) + 1).
// grid = (B*T/8, 16), block 256 (4 waves). Wave: 8 t-rows x 8 s-values.
// Lanes over d (8 chunks of 64). mo pre-scaled into registers.
// ---------------------------------------------------------------------------
#define LT 8
#define TANH_SCALE 2.885390081777927f  // 2*log2(e)
__global__ __launch_bounds__(256) void logits_kernel(
    const float* __restrict__ mo, const float* __restrict__ ma,
    const float* __restrict__ qw, const float* __restrict__ qb,
    float* __restrict__ logits) {
  int bt0 = blockIdx.x * LT;          // 8 consecutive (b,t), same b
  int b = bt0 >> 7;                   // T = 128
  int lane = threadIdx.x & 63;
  int wave = threadIdx.x >> 6;
  float moR[LT][8], qR[8];
  float qsum = 0.f;
#pragma unroll
  for (int i = 0; i < 8; ++i) {
    int dd = lane + 64 * i;
    float q = qw[dd];
    qR[i] = q;
    qsum += q;
#pragma unroll
    for (int t = 0; t < LT; ++t)
      moR[t][i] = mo[(size_t)(bt0 + t) * DD + dd] * TANH_SCALE;
  }
#pragma unroll
  for (int off = 32; off > 0; off >>= 1) qsum += __shfl_xor(qsum, off, 64);
  float base = qsum + qb[0];
  const float* maB = ma + (size_t)b * SS * DD;
  int s0 = blockIdx.y * 32 + wave * 8;
  for (int s = s0; s < s0 + 8; ++s) {
    float acc[LT] = {};
#pragma unroll
    for (int i = 0; i < 8; ++i) {
      float v = maB[(size_t)s * DD + lane + 64 * i] * TANH_SCALE;
#pragma unroll
      for (int t = 0; t < LT; ++t) {
        float e = __builtin_amdgcn_exp2f(moR[t][i] + v);
        float r = __builtin_amdgcn_rcpf(e + 1.0f);
        acc[t] = fmaf(qR[i], r, acc[t]);
      }
    }
    // two-phase reduce: butterfly bits {5,4,3} on all 8 accs,
    // select acc[lane>>3], butterfly bits {2,1,0}.
#pragma unroll
    for (int t = 0; t < LT; ++t) {
      acc[t] += __shfl_xor(acc[t], 32, 64);
      acc[t] += __shfl_xor(acc[t], 16, 64);
      acc[t] += __shfl_xor(acc[t], 8, 64);
    }
    int t = lane >> 3;
    float x = t >= 4 ? (t >= 6 ? (t == 7 ? acc[7] : acc[6])
                               : (t == 5 ? acc[5] : acc[4]))
                     : (t >= 2 ? (t == 3 ? acc[3] : acc[2])
                               : (t == 1 ? acc[1] : acc[0]));
    x += __shfl_xor(x, 4, 64);
    x += __shfl_xor(x, 2, 64);
    x += __shfl_xor(x, 1, 64);
    if ((lane & 7) == 0)
      logits[(size_t)(bt0 + t) * SS + s] = fmaf(-2.f, x, base);
  }
}

// ---------------------------------------------------------------------------
// softmax over rows of 512. grid = B*T, block = 256 (2 elems/thread).
// ---------------------------------------------------------------------------
__global__ __launch_bounds__(256) void softmax_kernel(
    const float* __restrict__ logits, float* __restrict__ attn) {
  int row = blockIdx.x;
  const float* lp = logits + (size_t)row * SS;
  int lane = threadIdx.x & 63, wave = threadIdx.x >> 6;
  float v0 = lp[threadIdx.x], v1 = lp[threadIdx.x + 256];
  float m = fmaxf(v0, v1);
  __shared__ float redm[4], reds[4];
#pragma unroll
  for (int off = 32; off > 0; off >>= 1) m = fmaxf(m, __shfl_xor(m, off, 64));
  if (lane == 0) redm[wave] = m;
  __syncthreads();
  m = fmaxf(fmaxf(redm[0], redm[1]), fmaxf(redm[2], redm[3]));
  float e0 = __builtin_amdgcn_exp2f((v0 - m) * 1.4426950408889634f);
  float e1 = __builtin_amdgcn_exp2f((v1 - m) * 1.4426950408889634f);
  float ssum = e0 + e1;
#pragma unroll
  for (int off = 32; off > 0; off >>= 1) ssum += __shfl_xor(ssum, off, 64);
  if (lane == 0) reds[wave] = ssum;
  __syncthreads();
  ssum = reds[0] + reds[1] + reds[2] + reds[3];
  float inv = 1.0f / ssum;
  attn[(size_t)row * SS + threadIdx.x] = e0 * inv;
  attn[(size_t)row * SS + threadIdx.x + 256] = e1 * inv;
}

// ---------------------------------------------------------------------------
// out[b,t,d] = tanh( [mix, output] @ out_w + out_b )   (K = 1024)
// same col-thread layout as gemm512. grid = B*T/RN.
// ---------------------------------------------------------------------------
template<int RN>
__global__ __launch_bounds__(256) void final_kernel(
    const float* __restrict__ mixo, const float* __restrict__ output,
    const float* __restrict__ out_w, const float* __restrict__ out_b,
    float* __restrict__ out) {
  constexpr int RH = RN / 2;
  int n0 = blockIdx.x * RN;
  int tx = threadIdx.x & 127;
  int half = threadIdx.x >> 7;
  int d0 = tx * 4;
  __shared__ float cs[RN][1024];
  for (int idx = threadIdx.x; idx < RN * 512; idx += 256) {
    int r = idx >> 9, k = idx & 511;
    cs[r][k] = mixo[(size_t)(n0 + r) * 512 + k];
    cs[r][512 + k] = output[(size_t)(n0 + r) * 512 + k];
  }
  __syncthreads();
  const float* wp = out_w + d0;
  float acc[RH][4] = {};
  for (int k0 = 0; k0 < 1024; k0 += 4) {
    F4 w[4];
#pragma unroll
    for (int j = 0; j < 4; ++j) w[j] = *(const F4*)&wp[(size_t)(k0 + j) * 512];
#pragma unroll
    for (int r = 0; r < RH; ++r) {
      F4 xv = *(const F4*)&cs[half * RH + r][k0];
#pragma unroll
      for (int j = 0; j < 4; ++j)
#pragma unroll
        for (int c = 0; c < 4; ++c)
          acc[r][c] = fmaf(xv.v[j], w[j].v[c], acc[r][c]);
    }
  }
#pragma unroll
  for (int r = 0; r < RH; ++r) {
    F4 o;
#pragma unroll
    for (int c = 0; c < 4; ++c) {
      float x = acc[r][c] + out_b[d0 + c];
      float e = __builtin_amdgcn_exp2f(x * TANH_SCALE);
      o.v[c] = fmaf(-2.f, __builtin_amdgcn_rcpf(e + 1.0f), 1.0f);
    }
    *(F4*)&out[(size_t)(n0 + half * RH + r) * 512 + d0] = o;
  }
}

extern "C" void kernel_launch(void* const* d_in, const int* in_sizes, int n_in,
                              void* d_out, int out_size, void* d_ws, size_t ws_size,
                              hipStream_t stream) {
  const float* output  = (const float*)d_in[0];  // [B,T,D]
  const float* context = (const float*)d_in[1];  // [B,S,C]
  const float* dec_w   = (const float*)d_in[2];  // [D,D]
  const float* dec_b   = (const float*)d_in[3];
  const float* attn_w  = (const float*)d_in[4];  // [C,D]
  const float* attn_b  = (const float*)d_in[5];
  const float* qw      = (const float*)d_in[6];  // [D,1]
  const float* qb      = (const float*)d_in[7];  // [1]
  const float* out_w   = (const float*)d_in[8];  // [1024,512]
  const float* out_b   = (const float*)d_in[9];

  float* out_p  = (float*)d_out;                       // [B,T,D]
  float* attn_p = out_p + (size_t)BB * TT_DIM * DD;    // [B,T,S]

  float* ws    = (float*)d_ws;
  float* mo    = ws;                                   // B*T*D
  float* ma    = mo + (size_t)BB * TT_DIM * DD;        // B*S*D
  float* logit = ma + (size_t)BB * SS * DD;            // B*T*S
  float* mixo  = logit + (size_t)BB * TT_DIM * SS;     // B*T*C

  gemm512<4, false><<<dim3(BB * TT_DIM / 4), 256, 0, stream>>>(output, dec_w, dec_b, mo);
  gemm512<8, false><<<dim3(BB * SS / 8), 256, 0, stream>>>(context, attn_w, attn_b, ma);
  logits_kernel<<<dim3(BB * TT_DIM / LT, 16), 256, 0, stream>>>(mo, ma, qw, qb, logit);
  softmax_kernel<<<dim3(BB * TT_DIM), 256, 0, stream>>>(logit, attn_p);
  gemm512<4, true><<<dim3(BB * TT_DIM / 4), 256, 0, stream>>>(attn_p, context, nullptr, mixo);
  final_kernel<4><<<dim3(BB * TT_DIM / 4), 256, 0, stream>>>(mixo, output, out_w, out_b, out_p);
}

// Round 3
// 131.178 us; speedup vs baseline: 1.9228x; 1.9228x over previous
//
#include <hip/hip_runtime.h>

#define BB 8
#define TT_DIM 128
#define SS 512
#define DD 512

typedef unsigned short u16;
typedef short short8 __attribute__((ext_vector_type(8)));
typedef short short4v __attribute__((ext_vector_type(4)));
typedef float f32x4 __attribute__((ext_vector_type(4)));

__device__ __forceinline__ u16 f2bf(float f) {
  union { float f; unsigned u; } v; v.f = f;
  return (u16)((v.u + 0x7FFFu + ((v.u >> 16) & 1u)) >> 16);
}

// ---------------------------------------------------------------------------
// fp32 -> bf16 bulk convert (n4 = elems/4)
// ---------------------------------------------------------------------------
__global__ __launch_bounds__(256) void cvt_bf16(const float* __restrict__ x,
                                                u16* __restrict__ y, int n4) {
  int stride = gridDim.x * 256;
  for (int i = blockIdx.x * 256 + threadIdx.x; i < n4; i += stride) {
    f32x4 v = ((const f32x4*)x)[i];
    short4v o;
    o[0] = (short)f2bf(v[0]); o[1] = (short)f2bf(v[1]);
    o[2] = (short)f2bf(v[2]); o[3] = (short)f2bf(v[3]);
    ((short4v*)y)[i] = o;
  }
}

// ---------------------------------------------------------------------------
// MFMA GEMM: Y[m,n] = sum_k A[m,k] * B[k,n] (+bias) (opt tanh)
// N = 512 fixed, lda = 512 (bf16 A), B row-major [K,512].
// 64x64 block tile, 4 waves (2x2), wave = 32x32 via 2x2 mfma 16x16x32.
// BSRC_F32: B is fp32 (converted during staging). OUT_BF: Y is bf16.
// CONCAT: k<512 from A1, k>=512 from A2. Batched via blockIdx.z + strides.
// ---------------------------------------------------------------------------
template<bool BSRC_F32, bool OUT_BF, bool DO_TANH, bool CONCAT, bool HASBIAS>
__global__ __launch_bounds__(256) void gemm_mfma(
    const u16* __restrict__ A1, const u16* __restrict__ A2,
    const void* __restrict__ Bsrc, const float* __restrict__ bias,
    void* __restrict__ Y, int K,
    size_t aBatch, size_t bBatch, size_t yBatch) {
  __shared__ u16 As[64][40];
  __shared__ u16 Bs[64][40];
  int b = blockIdx.z;
  int m0 = blockIdx.x * 64, n0 = blockIdx.y * 64;
  int t = threadIdx.x;
  int lane = t & 63, wid = t >> 6, wm = wid >> 1, wn = wid & 1;

  const f32x4 fzero = {0.f, 0.f, 0.f, 0.f};
  f32x4 acc[2][2];
#pragma unroll
  for (int i = 0; i < 2; ++i)
#pragma unroll
    for (int j = 0; j < 2; ++j) acc[i][j] = fzero;

  int ar = t >> 2, ac = (t & 3) * 8;   // A staging: row, col0 (8 bf16)
  int bn = t & 63, bk = (t >> 6) * 8;  // B staging: col(n), k0 (8 k's)
  int fr = lane & 15, fh = (lane >> 4) * 8;

  for (int k0 = 0; k0 < K; k0 += 32) {
    // ---- issue global loads ----
    const u16* ap;
    if (CONCAT && k0 >= 512)
      ap = A2 + (size_t)(m0 + ar) * 512 + (k0 - 512) + ac;
    else
      ap = A1 + (size_t)b * aBatch + (size_t)(m0 + ar) * 512 + k0 + ac;
    short8 av = *(const short8*)ap;

    short8 bv;
    if (BSRC_F32) {
      const float* bp = (const float*)Bsrc + (size_t)(k0 + bk) * 512 + n0 + bn;
#pragma unroll
      for (int i = 0; i < 8; ++i) bv[i] = (short)f2bf(bp[(size_t)i * 512]);
    } else {
      const u16* bp = (const u16*)Bsrc + (size_t)b * bBatch +
                      (size_t)(k0 + bk) * 512 + n0 + bn;
#pragma unroll
      for (int i = 0; i < 8; ++i) bv[i] = (short)bp[(size_t)i * 512];
    }

    if (k0) __syncthreads();
    *(short8*)&As[ar][ac] = av;
    *(short8*)&Bs[bn][bk] = bv;
    __syncthreads();

    short8 a0 = *(const short8*)&As[wm * 32 + fr][fh];
    short8 a1 = *(const short8*)&As[wm * 32 + 16 + fr][fh];
    short8 b0 = *(const short8*)&Bs[wn * 32 + fr][fh];
    short8 b1 = *(const short8*)&Bs[wn * 32 + 16 + fr][fh];
    acc[0][0] = __builtin_amdgcn_mfma_f32_16x16x32_bf16(a0, b0, acc[0][0], 0, 0, 0);
    acc[0][1] = __builtin_amdgcn_mfma_f32_16x16x32_bf16(a0, b1, acc[0][1], 0, 0, 0);
    acc[1][0] = __builtin_amdgcn_mfma_f32_16x16x32_bf16(a1, b0, acc[1][0], 0, 0, 0);
    acc[1][1] = __builtin_amdgcn_mfma_f32_16x16x32_bf16(a1, b1, acc[1][1], 0, 0, 0);
  }

  // ---- epilogue: C/D layout (m89): col = lane&15, row = (lane>>4)*4 + j ----
#pragma unroll
  for (int qa = 0; qa < 2; ++qa) {
    int row0 = m0 + wm * 32 + qa * 16 + ((lane >> 4) << 2);
#pragma unroll
    for (int qb = 0; qb < 2; ++qb) {
      int col = n0 + wn * 32 + qb * 16 + (lane & 15);
      float bvs = HASBIAS ? bias[col] : 0.0f;
#pragma unroll
      for (int j = 0; j < 4; ++j) {
        float v = acc[qa][qb][j] + bvs;
        if (DO_TANH) {
          float e = __builtin_amdgcn_exp2f(v * 2.885390081777927f);
          v = fmaf(-2.0f, __builtin_amdgcn_rcpf(e + 1.0f), 1.0f);
        }
        size_t off = (size_t)b * yBatch + (size_t)(row0 + j) * 512 + col;
        if (OUT_BF) ((u16*)Y)[off] = f2bf(v);
        else ((float*)Y)[off] = v;
      }
    }
  }
}

// ---------------------------------------------------------------------------
// logits[b,t,s] = sum_d tanh(mo+ma)*q + qb  =  Qsum + qb - 2*sum_d q*r
// r = 1/(exp2(2*log2e*(mo+ma)) + 1). grid = (B*T/8, 16), block 256.
// ---------------------------------------------------------------------------
#define LT 8
#define TANH_SCALE 2.885390081777927f  // 2*log2(e)
__global__ __launch_bounds__(256) void logits_kernel(
    const float* __restrict__ mo, const float* __restrict__ ma,
    const float* __restrict__ qw, const float* __restrict__ qb,
    float* __restrict__ logits) {
  int bt0 = blockIdx.x * LT;
  int b = bt0 >> 7;  // T = 128
  int lane = threadIdx.x & 63;
  int wave = threadIdx.x >> 6;
  float moR[LT][8], qR[8];
  float qsum = 0.f;
#pragma unroll
  for (int i = 0; i < 8; ++i) {
    int dd = lane + 64 * i;
    float q = qw[dd];
    qR[i] = q;
    qsum += q;
#pragma unroll
    for (int t = 0; t < LT; ++t)
      moR[t][i] = mo[(size_t)(bt0 + t) * DD + dd] * TANH_SCALE;
  }
#pragma unroll
  for (int off = 32; off > 0; off >>= 1) qsum += __shfl_xor(qsum, off, 64);
  float base = qsum + qb[0];
  const float* maB = ma + (size_t)b * SS * DD;
  int s0 = blockIdx.y * 32 + wave * 8;
  for (int s = s0; s < s0 + 8; ++s) {
    float acc[LT] = {};
#pragma unroll
    for (int i = 0; i < 8; ++i) {
      float v = maB[(size_t)s * DD + lane + 64 * i] * TANH_SCALE;
#pragma unroll
      for (int t = 0; t < LT; ++t) {
        float e = __builtin_amdgcn_exp2f(moR[t][i] + v);
        float r = __builtin_amdgcn_rcpf(e + 1.0f);
        acc[t] = fmaf(qR[i], r, acc[t]);
      }
    }
#pragma unroll
    for (int t = 0; t < LT; ++t) {
      acc[t] += __shfl_xor(acc[t], 32, 64);
      acc[t] += __shfl_xor(acc[t], 16, 64);
      acc[t] += __shfl_xor(acc[t], 8, 64);
    }
    int t = lane >> 3;
    float x = t >= 4 ? (t >= 6 ? (t == 7 ? acc[7] : acc[6])
                               : (t == 5 ? acc[5] : acc[4]))
                     : (t >= 2 ? (t == 3 ? acc[3] : acc[2])
                               : (t == 1 ? acc[1] : acc[0]));
    x += __shfl_xor(x, 4, 64);
    x += __shfl_xor(x, 2, 64);
    x += __shfl_xor(x, 1, 64);
    if ((lane & 7) == 0)
      logits[(size_t)(bt0 + t) * SS + s] = fmaf(-2.f, x, base);
  }
}

// ---------------------------------------------------------------------------
// softmax over rows of 512; writes fp32 attn (output) + bf16 copy (for mix).
// ---------------------------------------------------------------------------
__global__ __launch_bounds__(256) void softmax_kernel(
    const float* __restrict__ logits, float* __restrict__ attn,
    u16* __restrict__ attn_bf) {
  int row = blockIdx.x;
  const float* lp = logits + (size_t)row * SS;
  int lane = threadIdx.x & 63, wave = threadIdx.x >> 6;
  float v0 = lp[threadIdx.x], v1 = lp[threadIdx.x + 256];
  float m = fmaxf(v0, v1);
  __shared__ float redm[4], reds[4];
#pragma unroll
  for (int off = 32; off > 0; off >>= 1) m = fmaxf(m, __shfl_xor(m, off, 64));
  if (lane == 0) redm[wave] = m;
  __syncthreads();
  m = fmaxf(fmaxf(redm[0], redm[1]), fmaxf(redm[2], redm[3]));
  float e0 = __builtin_amdgcn_exp2f((v0 - m) * 1.4426950408889634f);
  float e1 = __builtin_amdgcn_exp2f((v1 - m) * 1.4426950408889634f);
  float ssum = e0 + e1;
#pragma unroll
  for (int off = 32; off > 0; off >>= 1) ssum += __shfl_xor(ssum, off, 64);
  if (lane == 0) reds[wave] = ssum;
  __syncthreads();
  ssum = reds[0] + reds[1] + reds[2] + reds[3];
  float inv = 1.0f / ssum;
  float a0 = e0 * inv, a1 = e1 * inv;
  attn[(size_t)row * SS + threadIdx.x] = a0;
  attn[(size_t)row * SS + threadIdx.x + 256] = a1;
  attn_bf[(size_t)row * SS + threadIdx.x] = f2bf(a0);
  attn_bf[(size_t)row * SS + threadIdx.x + 256] = f2bf(a1);
}

extern "C" void kernel_launch(void* const* d_in, const int* in_sizes, int n_in,
                              void* d_out, int out_size, void* d_ws, size_t ws_size,
                              hipStream_t stream) {
  const float* output  = (const float*)d_in[0];  // [B,T,D]
  const float* context = (const float*)d_in[1];  // [B,S,C]
  const float* dec_w   = (const float*)d_in[2];  // [D,D]
  const float* dec_b   = (const float*)d_in[3];
  const float* attn_w  = (const float*)d_in[4];  // [C,D]
  const float* attn_b  = (const float*)d_in[5];
  const float* qw      = (const float*)d_in[6];  // [D,1]
  const float* qb      = (const float*)d_in[7];  // [1]
  const float* out_w   = (const float*)d_in[8];  // [1024,512]
  const float* out_b   = (const float*)d_in[9];

  float* out_p  = (float*)d_out;                     // [B,T,D]
  float* attn_p = out_p + (size_t)BB * TT_DIM * DD;  // [B,T,S]

  char* p = (char*)d_ws;
  float* mo    = (float*)p; p += (size_t)BB * TT_DIM * DD * 4;  // 2MB
  float* ma    = (float*)p; p += (size_t)BB * SS * DD * 4;      // 8MB
  float* logit = (float*)p; p += (size_t)BB * TT_DIM * SS * 4;  // 2MB
  u16* output_bf  = (u16*)p; p += (size_t)BB * TT_DIM * DD * 2;
  u16* context_bf = (u16*)p; p += (size_t)BB * SS * DD * 2;
  u16* attn_bf    = (u16*)p; p += (size_t)BB * TT_DIM * SS * 2;
  u16* mixo_bf    = (u16*)p; p += (size_t)BB * TT_DIM * DD * 2;

  cvt_bf16<<<512, 256, 0, stream>>>(output, output_bf, BB * TT_DIM * DD / 4);
  cvt_bf16<<<1024, 256, 0, stream>>>(context, context_bf, BB * SS * DD / 4);

  // mo = output_bf @ dec_w + dec_b     [1024,512] fp32
  gemm_mfma<true, false, false, false, true><<<dim3(16, 8, 1), 256, 0, stream>>>(
      output_bf, nullptr, dec_w, dec_b, mo, 512, 0, 0, 0);
  // ma = context_bf @ attn_w + attn_b  [4096,512] fp32
  gemm_mfma<true, false, false, false, true><<<dim3(64, 8, 1), 256, 0, stream>>>(
      context_bf, nullptr, attn_w, attn_b, ma, 512, 0, 0, 0);

  logits_kernel<<<dim3(BB * TT_DIM / LT, 16), 256, 0, stream>>>(mo, ma, qw, qb, logit);
  softmax_kernel<<<dim3(BB * TT_DIM), 256, 0, stream>>>(logit, attn_p, attn_bf);

  // mix = attn_bf @ context_bf (batched) -> mixo_bf [8][128,512] bf16
  gemm_mfma<false, true, false, false, false><<<dim3(2, 8, 8), 256, 0, stream>>>(
      attn_bf, nullptr, context_bf, nullptr, mixo_bf, 512,
      (size_t)TT_DIM * 512, (size_t)SS * 512, (size_t)TT_DIM * 512);
  // out = tanh([mixo_bf, output_bf] @ out_w + out_b)  [1024,512] fp32
  gemm_mfma<true, false, true, true, true><<<dim3(16, 8, 1), 256, 0, stream>>>(
      mixo_bf, output_bf, out_w, out_b, out_p, 1024, 0, 0, 0);
}

// Round 4
// 110.007 us; speedup vs baseline: 2.2929x; 1.1924x over previous
//
#include <hip/hip_runtime.h>

#define BB 8
#define TT_DIM 128
#define SS 512
#define DD 512
#define TANH_SCALE 2.885390081777927f  // 2*log2(e)

typedef unsigned short u16;
typedef short short8 __attribute__((ext_vector_type(8)));
typedef float f32x4 __attribute__((ext_vector_type(4)));

__device__ __forceinline__ u16 f2bf(float f) {
  union { float f; unsigned u; } v; v.f = f;
  return (u16)((v.u + 0x7FFFu + ((v.u >> 16) & 1u)) >> 16);
}
__device__ __forceinline__ short8 cvt8(f32x4 a, f32x4 b) {
  short8 o;
  o[0] = (short)f2bf(a[0]); o[1] = (short)f2bf(a[1]);
  o[2] = (short)f2bf(a[2]); o[3] = (short)f2bf(a[3]);
  o[4] = (short)f2bf(b[0]); o[5] = (short)f2bf(b[1]);
  o[6] = (short)f2bf(b[2]); o[7] = (short)f2bf(b[3]);
  return o;
}

// ---------------------------------------------------------------------------
// Shared MFMA GEMM body. 64x64 tile, 4 waves (2x2), wave=32x32 via 2x2
// mfma_f32_16x16x32_bf16. All matrices have row stride 512.
// A_BF: A1 is bf16 (else fp32, converted in staging).
// CONCAT: k<512 from A1, k>=512 from A2 (fp32).
// EPI: 0 none, 1 exp2(TANH_SCALE*x)  [E = e^{2x}], 2 tanh.
// Software-pipelined: next k-tile loaded to regs during MFMA phase.
// ---------------------------------------------------------------------------
template<bool A_BF, bool CONCAT, bool OUT_BF, int EPI, bool HASBIAS>
__device__ __forceinline__ void gemm_body(
    const void* __restrict__ A1v, const float* __restrict__ A2,
    const float* __restrict__ B, const float* __restrict__ bias,
    void* __restrict__ Y, int K, int m0, int n0) {
  __shared__ u16 As[64][40];
  __shared__ u16 Bs[64][40];
  int t = threadIdx.x;
  int lane = t & 63, wid = t >> 6, wm = wid >> 1, wn = wid & 1;
  int ar = t >> 2, ac = (t & 3) * 8;   // A staging: row, col0
  int bn = t & 63, bk0 = (t >> 6) * 8; // B staging: col(n), first k
  int fr = lane & 15, fh = (lane >> 4) * 8;

  const f32x4 fzero = {0.f, 0.f, 0.f, 0.f};
  f32x4 acc[2][2];
#pragma unroll
  for (int i = 0; i < 2; ++i)
#pragma unroll
    for (int j = 0; j < 2; ++j) acc[i][j] = fzero;

  short8 av, bv;
  auto loadA = [&](int k0, short8& dst) {
    if (CONCAT && k0 >= 512) {
      const float* p = A2 + (size_t)(m0 + ar) * 512 + (k0 - 512) + ac;
      dst = cvt8(*(const f32x4*)p, *(const f32x4*)(p + 4));
    } else if (A_BF) {
      dst = *(const short8*)((const u16*)A1v + (size_t)(m0 + ar) * 512 + k0 + ac);
    } else {
      const float* p = (const float*)A1v + (size_t)(m0 + ar) * 512 + k0 + ac;
      dst = cvt8(*(const f32x4*)p, *(const f32x4*)(p + 4));
    }
  };
  auto loadB = [&](int k0, short8& dst) {
    const float* p = B + (size_t)(k0 + bk0) * 512 + n0 + bn;
#pragma unroll
    for (int i = 0; i < 8; ++i) dst[i] = (short)f2bf(p[(size_t)i * 512]);
  };

  loadA(0, av);
  loadB(0, bv);
  for (int k0 = 0; k0 < K; k0 += 32) {
    if (k0) __syncthreads();
    *(short8*)&As[ar][ac] = av;
    *(short8*)&Bs[bn][bk0] = bv;
    __syncthreads();
    short8 a0 = *(const short8*)&As[wm * 32 + fr][fh];
    short8 a1 = *(const short8*)&As[wm * 32 + 16 + fr][fh];
    short8 b0 = *(const short8*)&Bs[wn * 32 + fr][fh];
    short8 b1 = *(const short8*)&Bs[wn * 32 + 16 + fr][fh];
    if (k0 + 32 < K) {  // prefetch next tile; latency hides under MFMAs
      loadA(k0 + 32, av);
      loadB(k0 + 32, bv);
    }
    acc[0][0] = __builtin_amdgcn_mfma_f32_16x16x32_bf16(a0, b0, acc[0][0], 0, 0, 0);
    acc[0][1] = __builtin_amdgcn_mfma_f32_16x16x32_bf16(a0, b1, acc[0][1], 0, 0, 0);
    acc[1][0] = __builtin_amdgcn_mfma_f32_16x16x32_bf16(a1, b0, acc[1][0], 0, 0, 0);
    acc[1][1] = __builtin_amdgcn_mfma_f32_16x16x32_bf16(a1, b1, acc[1][1], 0, 0, 0);
  }

  // C/D layout (m89): col = lane&15, row = (lane>>4)*4 + j
#pragma unroll
  for (int qa = 0; qa < 2; ++qa) {
    int row0 = m0 + wm * 32 + qa * 16 + ((lane >> 4) << 2);
#pragma unroll
    for (int qn = 0; qn < 2; ++qn) {
      int col = n0 + wn * 32 + qn * 16 + (lane & 15);
      float bvs = HASBIAS ? bias[col] : 0.0f;
#pragma unroll
      for (int j = 0; j < 4; ++j) {
        float v = acc[qa][qn][j] + bvs;
        if (EPI == 1) {
          v = __builtin_amdgcn_exp2f(v * TANH_SCALE);
        } else if (EPI == 2) {
          float e = __builtin_amdgcn_exp2f(v * TANH_SCALE);
          v = fmaf(-2.0f, __builtin_amdgcn_rcpf(e + 1.0f), 1.0f);
        }
        size_t off = (size_t)(row0 + j) * 512 + col;
        if (OUT_BF) ((u16*)Y)[off] = f2bf(v);
        else ((float*)Y)[off] = v;
      }
    }
  }
}

// merged map-GEMMs: blocks [0,16) -> E = exp(2*(output@dec_w+dec_b)),
//                   blocks [16,80) -> F = exp(2*(context@attn_w+attn_b))
__global__ __launch_bounds__(256) void ef_gemm(
    const float* __restrict__ output, const float* __restrict__ dec_w,
    const float* __restrict__ dec_b, const float* __restrict__ context,
    const float* __restrict__ attn_w, const float* __restrict__ attn_b,
    float* __restrict__ E, float* __restrict__ F) {
  bool isE = blockIdx.x < 16;
  gemm_body<false, false, false, 1, true>(
      isE ? output : context, nullptr, isE ? dec_w : attn_w,
      isE ? dec_b : attn_b, isE ? (void*)E : (void*)F, 512,
      (int)(isE ? blockIdx.x : blockIdx.x - 16) * 64, blockIdx.y * 64);
}

// mix = attn @ context (batched) -> bf16
__global__ __launch_bounds__(256) void mix_gemm(
    const float* __restrict__ attn, const float* __restrict__ context,
    u16* __restrict__ mixo) {
  int b = blockIdx.z;
  gemm_body<false, false, true, 0, false>(
      attn + (size_t)b * TT_DIM * SS, nullptr, context + (size_t)b * SS * DD,
      nullptr, mixo + (size_t)b * TT_DIM * DD, 512,
      blockIdx.x * 64, blockIdx.y * 64);
}

// out = tanh([mixo, output] @ out_w + out_b), K = 1024
__global__ __launch_bounds__(256) void final_gemm(
    const u16* __restrict__ mixo, const float* __restrict__ output,
    const float* __restrict__ out_w, const float* __restrict__ out_b,
    float* __restrict__ out) {
  gemm_body<true, true, false, 2, true>(mixo, output, out_w, out_b, out, 1024,
                                        blockIdx.x * 64, blockIdx.y * 64);
}

// ---------------------------------------------------------------------------
// logits[b,t,s] = Sq + qb - 2*sum_d q_d / (E[t,d]*F[s,d] + 1)
// grid (B*T/8, 16), block 256 (4 waves). Wave: 8 t-rows x 8 s-values.
// Lanes over d. E rows in registers; F rows double-buffered.
// ---------------------------------------------------------------------------
__global__ __launch_bounds__(256) void logits_kernel(
    const float* __restrict__ E, const float* __restrict__ F,
    const float* __restrict__ qw, const float* __restrict__ qb,
    float* __restrict__ logits) {
  int bt0 = blockIdx.x * 8;
  int b = bt0 >> 7;  // T = 128
  int lane = threadIdx.x & 63;
  int wave = threadIdx.x >> 6;
  float ER[8][8], qR[8];
  float qsum = 0.f;
#pragma unroll
  for (int i = 0; i < 8; ++i) {
    int dd = lane + 64 * i;
    float q = qw[dd];
    qR[i] = q;
    qsum += q;
#pragma unroll
    for (int tt = 0; tt < 8; ++tt)
      ER[tt][i] = E[(size_t)(bt0 + tt) * DD + dd];
  }
#pragma unroll
  for (int off = 32; off > 0; off >>= 1) qsum += __shfl_xor(qsum, off, 64);
  float base = qsum + qb[0];
  const float* Fb = F + (size_t)b * SS * DD;
  int s0 = blockIdx.y * 32 + wave * 8;

  float Fv[2][8];
#pragma unroll
  for (int i = 0; i < 8; ++i)
    Fv[0][i] = Fb[(size_t)s0 * DD + lane + 64 * i];

#pragma unroll
  for (int si = 0; si < 8; ++si) {
    const int cur = si & 1;
    if (si < 7) {
#pragma unroll
      for (int i = 0; i < 8; ++i)
        Fv[cur ^ 1][i] = Fb[(size_t)(s0 + si + 1) * DD + lane + 64 * i];
    }
    float acc[8] = {};
#pragma unroll
    for (int i = 0; i < 8; ++i) {
      float f = Fv[cur][i];
#pragma unroll
      for (int tt = 0; tt < 8; ++tt)
        acc[tt] = fmaf(qR[i],
                       __builtin_amdgcn_rcpf(fmaf(ER[tt][i], f, 1.0f)),
                       acc[tt]);
    }
#pragma unroll
    for (int tt = 0; tt < 8; ++tt) {
      acc[tt] += __shfl_xor(acc[tt], 32, 64);
      acc[tt] += __shfl_xor(acc[tt], 16, 64);
      acc[tt] += __shfl_xor(acc[tt], 8, 64);
    }
    int tt = lane >> 3;
    float x = tt >= 4 ? (tt >= 6 ? (tt == 7 ? acc[7] : acc[6])
                                 : (tt == 5 ? acc[5] : acc[4]))
                      : (tt >= 2 ? (tt == 3 ? acc[3] : acc[2])
                                 : (tt == 1 ? acc[1] : acc[0]));
    x += __shfl_xor(x, 4, 64);
    x += __shfl_xor(x, 2, 64);
    x += __shfl_xor(x, 1, 64);
    if ((lane & 7) == 0)
      logits[(size_t)(bt0 + tt) * SS + s0 + si] = fmaf(-2.f, x, base);
  }
}

// ---------------------------------------------------------------------------
// softmax over rows of 512. grid = B*T, block = 256 (2 elems/thread).
// ---------------------------------------------------------------------------
__global__ __launch_bounds__(256) void softmax_kernel(
    const float* __restrict__ logits, float* __restrict__ attn) {
  int row = blockIdx.x;
  const float* lp = logits + (size_t)row * SS;
  int lane = threadIdx.x & 63, wave = threadIdx.x >> 6;
  float v0 = lp[threadIdx.x], v1 = lp[threadIdx.x + 256];
  float m = fmaxf(v0, v1);
  __shared__ float redm[4], reds[4];
#pragma unroll
  for (int off = 32; off > 0; off >>= 1) m = fmaxf(m, __shfl_xor(m, off, 64));
  if (lane == 0) redm[wave] = m;
  __syncthreads();
  m = fmaxf(fmaxf(redm[0], redm[1]), fmaxf(redm[2], redm[3]));
  float e0 = __builtin_amdgcn_exp2f((v0 - m) * 1.4426950408889634f);
  float e1 = __builtin_amdgcn_exp2f((v1 - m) * 1.4426950408889634f);
  float ssum = e0 + e1;
#pragma unroll
  for (int off = 32; off > 0; off >>= 1) ssum += __shfl_xor(ssum, off, 64);
  if (lane == 0) reds[wave] = ssum;
  __syncthreads();
  ssum = reds[0] + reds[1] + reds[2] + reds[3];
  float inv = 1.0f / ssum;
  attn[(size_t)row * SS + threadIdx.x] = e0 * inv;
  attn[(size_t)row * SS + threadIdx.x + 256] = e1 * inv;
}

extern "C" void kernel_launch(void* const* d_in, const int* in_sizes, int n_in,
                              void* d_out, int out_size, void* d_ws, size_t ws_size,
                              hipStream_t stream) {
  const float* output  = (const float*)d_in[0];  // [B,T,D]
  const float* context = (const float*)d_in[1];  // [B,S,C]
  const float* dec_w   = (const float*)d_in[2];  // [D,D]
  const float* dec_b   = (const float*)d_in[3];
  const float* attn_w  = (const float*)d_in[4];  // [C,D]
  const float* attn_b  = (const float*)d_in[5];
  const float* qw      = (const float*)d_in[6];  // [D,1]
  const float* qb      = (const float*)d_in[7];  // [1]
  const float* out_w   = (const float*)d_in[8];  // [1024,512]
  const float* out_b   = (const float*)d_in[9];

  float* out_p  = (float*)d_out;                     // [B,T,D]
  float* attn_p = out_p + (size_t)BB * TT_DIM * DD;  // [B,T,S]

  char* p = (char*)d_ws;
  float* E     = (float*)p; p += (size_t)BB * TT_DIM * DD * 4;  // 2MB
  float* F     = (float*)p; p += (size_t)BB * SS * DD * 4;      // 8MB
  float* logit = (float*)p; p += (size_t)BB * TT_DIM * SS * 4;  // 2MB
  u16* mixo    = (u16*)p;   p += (size_t)BB * TT_DIM * DD * 2;  // 1MB

  // E and F map-GEMMs merged into one 640-block launch
  ef_gemm<<<dim3(80, 8), 256, 0, stream>>>(output, dec_w, dec_b,
                                           context, attn_w, attn_b, E, F);
  logits_kernel<<<dim3(BB * TT_DIM / 8, 16), 256, 0, stream>>>(E, F, qw, qb, logit);
  softmax_kernel<<<dim3(BB * TT_DIM), 256, 0, stream>>>(logit, attn_p);
  mix_gemm<<<dim3(2, 8, 8), 256, 0, stream>>>(attn_p, context, mixo);
  final_gemm<<<dim3(16, 8), 256, 0, stream>>>(mixo, output, out_w, out_b, out_p);
}

// Round 5
// 103.063 us; speedup vs baseline: 2.4474x; 1.0674x over previous
//
#include <hip/hip_runtime.h>

#define BB 8
#define TT_DIM 128
#define SS 512
#define DD 512
#define TANH_SCALE 2.885390081777927f   // 2*log2(e)
#define LOG2E 1.4426950408889634f

typedef unsigned short u16;
typedef short short8 __attribute__((ext_vector_type(8)));
typedef float f32x4 __attribute__((ext_vector_type(4)));

__device__ __forceinline__ u16 f2bf(float f) {
  union { float f; unsigned u; } v; v.f = f;
  return (u16)((v.u + 0x7FFFu + ((v.u >> 16) & 1u)) >> 16);
}
__device__ __forceinline__ short8 cvt8(f32x4 a, f32x4 b) {
  short8 o;
  o[0] = (short)f2bf(a[0]); o[1] = (short)f2bf(a[1]);
  o[2] = (short)f2bf(a[2]); o[3] = (short)f2bf(a[3]);
  o[4] = (short)f2bf(b[0]); o[5] = (short)f2bf(b[1]);
  o[6] = (short)f2bf(b[2]); o[7] = (short)f2bf(b[3]);
  return o;
}

// ---------------------------------------------------------------------------
// MFMA GEMM body, K=512, all row strides 512. 64x64 tile, 4 waves (2x2),
// wave = 32x32 via 2x2 mfma_f32_16x16x32_bf16. Reg-prefetched k-pipeline.
// A_BF: A is bf16 (else fp32, converted during staging).
// epi: 0 none, 1 exp(2x), 2 tanh.  Cadd: optional fp32 [.,512] added pre-epi.
// ---------------------------------------------------------------------------
template<bool A_BF, bool OUT_BF>
__device__ __forceinline__ void gemm_body(
    const void* __restrict__ Av, const float* __restrict__ B,
    const float* __restrict__ bias, const float* __restrict__ Cadd,
    void* __restrict__ Y, int m0, int n0, int epi) {
  __shared__ u16 As[64][40];
  __shared__ u16 Bs[64][40];
  int t = threadIdx.x;
  int lane = t & 63, wid = t >> 6, wm = wid >> 1, wn = wid & 1;
  int ar = t >> 2, ac = (t & 3) * 8;
  int bn = t & 63, bk0 = (t >> 6) * 8;
  int fr = lane & 15, fh = (lane >> 4) * 8;

  const f32x4 fzero = {0.f, 0.f, 0.f, 0.f};
  f32x4 acc[2][2];
#pragma unroll
  for (int i = 0; i < 2; ++i)
#pragma unroll
    for (int j = 0; j < 2; ++j) acc[i][j] = fzero;

  short8 av, bv;
  auto loadA = [&](int k0, short8& dst) {
    if (A_BF) {
      dst = *(const short8*)((const u16*)Av + (size_t)(m0 + ar) * 512 + k0 + ac);
    } else {
      const float* p = (const float*)Av + (size_t)(m0 + ar) * 512 + k0 + ac;
      dst = cvt8(*(const f32x4*)p, *(const f32x4*)(p + 4));
    }
  };
  auto loadB = [&](int k0, short8& dst) {
    const float* p = B + (size_t)(k0 + bk0) * 512 + n0 + bn;
#pragma unroll
    for (int i = 0; i < 8; ++i) dst[i] = (short)f2bf(p[(size_t)i * 512]);
  };

  loadA(0, av);
  loadB(0, bv);
  for (int k0 = 0; k0 < 512; k0 += 32) {
    if (k0) __syncthreads();
    *(short8*)&As[ar][ac] = av;
    *(short8*)&Bs[bn][bk0] = bv;
    __syncthreads();
    short8 a0 = *(const short8*)&As[wm * 32 + fr][fh];
    short8 a1 = *(const short8*)&As[wm * 32 + 16 + fr][fh];
    short8 b0 = *(const short8*)&Bs[wn * 32 + fr][fh];
    short8 b1 = *(const short8*)&Bs[wn * 32 + 16 + fr][fh];
    if (k0 + 32 < 512) {
      loadA(k0 + 32, av);
      loadB(k0 + 32, bv);
    }
    acc[0][0] = __builtin_amdgcn_mfma_f32_16x16x32_bf16(a0, b0, acc[0][0], 0, 0, 0);
    acc[0][1] = __builtin_amdgcn_mfma_f32_16x16x32_bf16(a0, b1, acc[0][1], 0, 0, 0);
    acc[1][0] = __builtin_amdgcn_mfma_f32_16x16x32_bf16(a1, b0, acc[1][0], 0, 0, 0);
    acc[1][1] = __builtin_amdgcn_mfma_f32_16x16x32_bf16(a1, b1, acc[1][1], 0, 0, 0);
  }

  // C/D layout (m89): col = lane&15, row = (lane>>4)*4 + j
#pragma unroll
  for (int qa = 0; qa < 2; ++qa) {
    int row0 = m0 + wm * 32 + qa * 16 + ((lane >> 4) << 2);
#pragma unroll
    for (int qn = 0; qn < 2; ++qn) {
      int col = n0 + wn * 32 + qn * 16 + (lane & 15);
      float bvs = bias ? bias[col] : 0.0f;
#pragma unroll
      for (int j = 0; j < 4; ++j) {
        float v = acc[qa][qn][j] + bvs;
        if (Cadd) v += Cadd[(size_t)(row0 + j) * 512 + col];
        if (epi == 1) {
          v = __builtin_amdgcn_exp2f(v * TANH_SCALE);
        } else if (epi == 2) {
          float e = __builtin_amdgcn_exp2f(v * TANH_SCALE);
          v = fmaf(-2.0f, __builtin_amdgcn_rcpf(e + 1.0f), 1.0f);
        }
        size_t off = (size_t)(row0 + j) * 512 + col;
        if (OUT_BF) ((u16*)Y)[off] = f2bf(v);
        else ((float*)Y)[off] = v;
      }
    }
  }
}

// blocks [0,16): E = exp(2*(output@dec_w+dec_b))      [1024,512]
// blocks [16,80): F = exp(2*(context@attn_w+attn_b))  [4096,512]
// blocks [80,96): G = output@out_w[512:] + out_b      [1024,512]
__global__ __launch_bounds__(256) void ef_gemm(
    const float* __restrict__ output, const float* __restrict__ dec_w,
    const float* __restrict__ dec_b, const float* __restrict__ context,
    const float* __restrict__ attn_w, const float* __restrict__ attn_b,
    const float* __restrict__ out_w, const float* __restrict__ out_b,
    float* __restrict__ E, float* __restrict__ F, float* __restrict__ G) {
  int bx = blockIdx.x;
  const float *A, *Bm, *bias;
  float* Y;
  int m0, epi;
  if (bx < 16)      { A = output;  Bm = dec_w;  bias = dec_b;  Y = E; m0 = bx * 64;        epi = 1; }
  else if (bx < 80) { A = context; Bm = attn_w; bias = attn_b; Y = F; m0 = (bx - 16) * 64; epi = 1; }
  else              { A = output;  Bm = out_w + 512 * 512; bias = out_b; Y = G; m0 = (bx - 80) * 64; epi = 0; }
  gemm_body<false, false>(A, Bm, bias, nullptr, Y, m0, blockIdx.y * 64, epi);
}

// mix = attn @ context (batched) -> bf16
__global__ __launch_bounds__(256) void mix_gemm(
    const float* __restrict__ attn, const float* __restrict__ context,
    u16* __restrict__ mixo) {
  int b = blockIdx.z;
  gemm_body<false, true>(attn + (size_t)b * TT_DIM * SS,
                         context + (size_t)b * SS * DD, nullptr, nullptr,
                         mixo + (size_t)b * TT_DIM * DD,
                         blockIdx.x * 64, blockIdx.y * 64, 0);
}

// out = tanh(mixo @ out_w[:512] + G)
__global__ __launch_bounds__(256) void final_gemm(
    const u16* __restrict__ mixo, const float* __restrict__ out_w,
    const float* __restrict__ G, float* __restrict__ out) {
  gemm_body<true, false>(mixo, out_w, nullptr, G, out,
                         blockIdx.x * 64, blockIdx.y * 64, 2);
}

// ---------------------------------------------------------------------------
// Fused logits + softmax.
// logits[t,s] = base - 2*sum_d q_d/(E[t,d]*F[s,d]+1); attn = softmax_s.
// grid = B*T/4 (256 blocks), block = 512 (8 waves). Block: 4 t x 512 s.
// Wave: 4 t x 64 s, lanes over d. Pairs of d share one rcp:
//   q1/x1 + q2/x2 = (q1*x2 + q2*x1)/(x1*x2).
// ---------------------------------------------------------------------------
__global__ __launch_bounds__(512, 2) void logits_softmax_kernel(
    const float* __restrict__ E, const float* __restrict__ F,
    const float* __restrict__ qw, const float* __restrict__ qb,
    float* __restrict__ attn) {
  int bt0 = blockIdx.x * 4;
  int b = bt0 >> 7;  // T = 128
  int tid = threadIdx.x;
  int lane = tid & 63, wave = tid >> 6;
  __shared__ float lg[4][516];
  __shared__ float redm[8], reds[8];

  float ER[4][8], qR[8];
  float qsum = 0.f;
#pragma unroll
  for (int i = 0; i < 8; ++i) {
    int dd = lane + 64 * i;
    float q = qw[dd];
    qR[i] = q;
    qsum += q;
#pragma unroll
    for (int t = 0; t < 4; ++t) ER[t][i] = E[(size_t)(bt0 + t) * DD + dd];
  }
#pragma unroll
  for (int off = 32; off > 0; off >>= 1) qsum += __shfl_xor(qsum, off, 64);
  float base = qsum + qb[0];

  const float* Fb = F + (size_t)b * SS * DD + lane;
  int s0 = wave * 64;

  auto process = [&](const float (&Fv)[8], int si) {
    float acc[4] = {0.f, 0.f, 0.f, 0.f};
#pragma unroll
    for (int i = 0; i < 8; i += 2) {
      float f1 = Fv[i], f2 = Fv[i + 1];
      float q1 = qR[i], q2 = qR[i + 1];
#pragma unroll
      for (int t = 0; t < 4; ++t) {
        float x1 = fmaf(ER[t][i], f1, 1.0f);
        float x2 = fmaf(ER[t][i + 1], f2, 1.0f);
        float num = fmaf(q2, x1, q1 * x2);
        acc[t] = fmaf(num, __builtin_amdgcn_rcpf(x1 * x2), acc[t]);
      }
    }
#pragma unroll
    for (int t = 0; t < 4; ++t) {
      acc[t] += __shfl_xor(acc[t], 32, 64);
      acc[t] += __shfl_xor(acc[t], 16, 64);
      acc[t] += __shfl_xor(acc[t], 8, 64);
    }
    int tt = (lane >> 3) & 3;
    float x = (tt & 1) ? ((tt & 2) ? acc[3] : acc[1])
                       : ((tt & 2) ? acc[2] : acc[0]);
    x += __shfl_xor(x, 4, 64);
    x += __shfl_xor(x, 2, 64);
    x += __shfl_xor(x, 1, 64);
    if ((lane & 7) == 0 && lane < 32)
      lg[tt][s0 + si] = fmaf(-2.f, x, base);
  };

  float Fa[8], Fbuf[8];
#pragma unroll
  for (int i = 0; i < 8; ++i) Fa[i] = Fb[(size_t)s0 * DD + 64 * i];
  for (int si = 0; si < 64; si += 2) {
#pragma unroll
    for (int i = 0; i < 8; ++i)
      Fbuf[i] = Fb[(size_t)(s0 + si + 1) * DD + 64 * i];
    process(Fa, si);
    if (si + 2 < 64) {
#pragma unroll
      for (int i = 0; i < 8; ++i)
        Fa[i] = Fb[(size_t)(s0 + si + 2) * DD + 64 * i];
    }
    process(Fbuf, si + 1);
  }
  __syncthreads();

  // ---- softmax over the 4 rows in LDS; 2 waves per row, 4 elems/thread ----
  int r = wave >> 1;
  int ci = (tid & 127) * 4;
  f32x4 v = *(const f32x4*)&lg[r][ci];
  float m = fmaxf(fmaxf(v[0], v[1]), fmaxf(v[2], v[3]));
#pragma unroll
  for (int off = 32; off > 0; off >>= 1) m = fmaxf(m, __shfl_xor(m, off, 64));
  if (lane == 0) redm[wave] = m;
  __syncthreads();
  m = fmaxf(redm[r * 2], redm[r * 2 + 1]);
  float e0 = __builtin_amdgcn_exp2f((v[0] - m) * LOG2E);
  float e1 = __builtin_amdgcn_exp2f((v[1] - m) * LOG2E);
  float e2 = __builtin_amdgcn_exp2f((v[2] - m) * LOG2E);
  float e3 = __builtin_amdgcn_exp2f((v[3] - m) * LOG2E);
  float ssum = (e0 + e1) + (e2 + e3);
#pragma unroll
  for (int off = 32; off > 0; off >>= 1) ssum += __shfl_xor(ssum, off, 64);
  if (lane == 0) reds[wave] = ssum;
  __syncthreads();
  float inv = __builtin_amdgcn_rcpf(reds[r * 2] + reds[r * 2 + 1]);
  f32x4 o;
  o[0] = e0 * inv; o[1] = e1 * inv; o[2] = e2 * inv; o[3] = e3 * inv;
  *(f32x4*)&attn[(size_t)(bt0 + r) * SS + ci] = o;
}

extern "C" void kernel_launch(void* const* d_in, const int* in_sizes, int n_in,
                              void* d_out, int out_size, void* d_ws, size_t ws_size,
                              hipStream_t stream) {
  const float* output  = (const float*)d_in[0];  // [B,T,D]
  const float* context = (const float*)d_in[1];  // [B,S,C]
  const float* dec_w   = (const float*)d_in[2];  // [D,D]
  const float* dec_b   = (const float*)d_in[3];
  const float* attn_w  = (const float*)d_in[4];  // [C,D]
  const float* attn_b  = (const float*)d_in[5];
  const float* qw      = (const float*)d_in[6];  // [D,1]
  const float* qb      = (const float*)d_in[7];  // [1]
  const float* out_w   = (const float*)d_in[8];  // [1024,512]
  const float* out_b   = (const float*)d_in[9];

  float* out_p  = (float*)d_out;                     // [B,T,D]
  float* attn_p = out_p + (size_t)BB * TT_DIM * DD;  // [B,T,S]

  char* p = (char*)d_ws;
  float* E  = (float*)p; p += (size_t)BB * TT_DIM * DD * 4;  // 2MB
  float* F  = (float*)p; p += (size_t)BB * SS * DD * 4;      // 8MB
  float* G  = (float*)p; p += (size_t)BB * TT_DIM * DD * 4;  // 2MB
  u16* mixo = (u16*)p;   p += (size_t)BB * TT_DIM * DD * 2;  // 1MB

  ef_gemm<<<dim3(96, 8), 256, 0, stream>>>(output, dec_w, dec_b, context,
                                           attn_w, attn_b, out_w, out_b,
                                           E, F, G);
  logits_softmax_kernel<<<dim3(BB * TT_DIM / 4), 512, 0, stream>>>(
      E, F, qw, qb, attn_p);
  mix_gemm<<<dim3(2, 8, 8), 256, 0, stream>>>(attn_p, context, mixo);
  final_gemm<<<dim3(16, 8), 256, 0, stream>>>(mixo, out_w, G, out_p);
}

// Round 6
// 100.622 us; speedup vs baseline: 2.5067x; 1.0243x over previous
//
#include <hip/hip_runtime.h>

#define BB 8
#define TT_DIM 128
#define SS 512
#define DD 512
#define TANH_SCALE 2.885390081777927f   // 2*log2(e)
#define LOG2E 1.4426950408889634f

typedef unsigned short u16;
typedef short short8 __attribute__((ext_vector_type(8)));
typedef float f32x4 __attribute__((ext_vector_type(4)));

__device__ __forceinline__ u16 f2bf(float f) {
  union { float f; unsigned u; } v; v.f = f;
  return (u16)((v.u + 0x7FFFu + ((v.u >> 16) & 1u)) >> 16);
}
__device__ __forceinline__ short8 cvt8(f32x4 a, f32x4 b) {
  short8 o;
  o[0] = (short)f2bf(a[0]); o[1] = (short)f2bf(a[1]);
  o[2] = (short)f2bf(a[2]); o[3] = (short)f2bf(a[3]);
  o[4] = (short)f2bf(b[0]); o[5] = (short)f2bf(b[1]);
  o[6] = (short)f2bf(b[2]); o[7] = (short)f2bf(b[3]);
  return o;
}

// ---------------------------------------------------------------------------
// 64x64 MFMA GEMM body (fp32 in, fp32 out), K=512, strides 512.
// epi=1: exp(2x). trout: write transposed per batch-512: Y[b][col][srow].
// ---------------------------------------------------------------------------
__device__ __forceinline__ void gemm64_body(
    const float* __restrict__ A, const float* __restrict__ B,
    const float* __restrict__ bias, float* __restrict__ Y,
    int m0, int n0, int epi, bool trout) {
  __shared__ u16 As[64][40];
  __shared__ u16 Bs[64][40];
  int t = threadIdx.x;
  int lane = t & 63, wid = t >> 6, wm = wid >> 1, wn = wid & 1;
  int ar = t >> 2, ac = (t & 3) * 8;
  int bn = t & 63, bk0 = (t >> 6) * 8;
  int fr = lane & 15, fh = (lane >> 4) * 8;

  const f32x4 fzero = {0.f, 0.f, 0.f, 0.f};
  f32x4 acc[2][2];
#pragma unroll
  for (int i = 0; i < 2; ++i)
#pragma unroll
    for (int j = 0; j < 2; ++j) acc[i][j] = fzero;

  short8 av, bv;
  auto loadA = [&](int k0) {
    const float* p = A + (size_t)(m0 + ar) * 512 + k0 + ac;
    av = cvt8(*(const f32x4*)p, *(const f32x4*)(p + 4));
  };
  auto loadB = [&](int k0) {
    const float* p = B + (size_t)(k0 + bk0) * 512 + n0 + bn;
#pragma unroll
    for (int i = 0; i < 8; ++i) bv[i] = (short)f2bf(p[(size_t)i * 512]);
  };

  loadA(0); loadB(0);
  for (int k0 = 0; k0 < 512; k0 += 32) {
    if (k0) __syncthreads();
    *(short8*)&As[ar][ac] = av;
    *(short8*)&Bs[bn][bk0] = bv;
    __syncthreads();
    short8 a0 = *(const short8*)&As[wm * 32 + fr][fh];
    short8 a1 = *(const short8*)&As[wm * 32 + 16 + fr][fh];
    short8 b0 = *(const short8*)&Bs[wn * 32 + fr][fh];
    short8 b1 = *(const short8*)&Bs[wn * 32 + 16 + fr][fh];
    if (k0 + 32 < 512) { loadA(k0 + 32); loadB(k0 + 32); }
    acc[0][0] = __builtin_amdgcn_mfma_f32_16x16x32_bf16(a0, b0, acc[0][0], 0, 0, 0);
    acc[0][1] = __builtin_amdgcn_mfma_f32_16x16x32_bf16(a0, b1, acc[0][1], 0, 0, 0);
    acc[1][0] = __builtin_amdgcn_mfma_f32_16x16x32_bf16(a1, b0, acc[1][0], 0, 0, 0);
    acc[1][1] = __builtin_amdgcn_mfma_f32_16x16x32_bf16(a1, b1, acc[1][1], 0, 0, 0);
  }

  // C/D layout (m89): col = lane&15, row = (lane>>4)*4 + j
#pragma unroll
  for (int qa = 0; qa < 2; ++qa) {
    int rbase = wm * 32 + qa * 16 + ((lane >> 4) << 2);
#pragma unroll
    for (int qn = 0; qn < 2; ++qn) {
      int col = n0 + wn * 32 + qn * 16 + (lane & 15);
      float bvs = bias[col];
      f32x4 v4;
#pragma unroll
      for (int j = 0; j < 4; ++j) {
        float v = acc[qa][qn][j] + bvs;
        if (epi) v = __builtin_amdgcn_exp2f(v * TANH_SCALE);
        v4[j] = v;
      }
      if (trout) {
        int bb = m0 >> 9;
        int srow = (m0 & 511) + rbase;
        *(f32x4*)&Y[((size_t)bb * 512 + col) * 512 + srow] = v4;
      } else {
#pragma unroll
        for (int j = 0; j < 4; ++j)
          Y[(size_t)(m0 + rbase + j) * 512 + col] = v4[j];
      }
    }
  }
}

// blocks [0,16): E = exp(2*(output@dec_w+dec_b))            [1024,512]
// blocks [16,80): Ft = exp(2*(context@attn_w+attn_b))^T     [8][512d][512s]
// blocks [80,96): G = output@out_w[512:] + out_b            [1024,512]
__global__ __launch_bounds__(256) void ef_gemm(
    const float* __restrict__ output, const float* __restrict__ dec_w,
    const float* __restrict__ dec_b, const float* __restrict__ context,
    const float* __restrict__ attn_w, const float* __restrict__ attn_b,
    const float* __restrict__ out_w, const float* __restrict__ out_b,
    float* __restrict__ E, float* __restrict__ Ft, float* __restrict__ G) {
  int bx = blockIdx.x;
  const float *A, *Bm, *bias;
  float* Y;
  int m0, epi;
  bool tr;
  if (bx < 16)      { A = output;  Bm = dec_w;  bias = dec_b;  Y = E;  m0 = bx * 64;        epi = 1; tr = false; }
  else if (bx < 80) { A = context; Bm = attn_w; bias = attn_b; Y = Ft; m0 = (bx - 16) * 64; epi = 1; tr = true; }
  else              { A = output;  Bm = out_w + 512 * 512; bias = out_b; Y = G; m0 = (bx - 80) * 64; epi = 0; tr = false; }
  gemm64_body(A, Bm, bias, Y, m0, blockIdx.y * 64, epi, tr);
}

// ---------------------------------------------------------------------------
// 32x64 MFMA GEMM body: more blocks for small GEMMs. 4 waves 2x2, wave=16x32.
// ---------------------------------------------------------------------------
template<bool A_BF, bool OUT_BF>
__device__ __forceinline__ void gemm32_body(
    const void* __restrict__ Av, const float* __restrict__ B,
    const float* __restrict__ Cadd, void* __restrict__ Y,
    int m0, int n0, bool do_tanh) {
  __shared__ u16 As[32][40];
  __shared__ u16 Bs[64][40];
  int t = threadIdx.x;
  int lane = t & 63, wid = t >> 6, wm = wid >> 1, wn = wid & 1;
  int ar = t >> 2, ac = (t & 3) * 8;   // threads < 128 stage A
  int bn = t & 63, bk0 = (t >> 6) * 8;
  int fr = lane & 15, fh = (lane >> 4) * 8;

  const f32x4 fzero = {0.f, 0.f, 0.f, 0.f};
  f32x4 acc[2] = {fzero, fzero};

  short8 av, bv;
  auto loadA = [&](int k0) {
    if (t < 128) {
      if (A_BF) {
        av = *(const short8*)((const u16*)Av + (size_t)(m0 + ar) * 512 + k0 + ac);
      } else {
        const float* p = (const float*)Av + (size_t)(m0 + ar) * 512 + k0 + ac;
        av = cvt8(*(const f32x4*)p, *(const f32x4*)(p + 4));
      }
    }
  };
  auto loadB = [&](int k0) {
    const float* p = B + (size_t)(k0 + bk0) * 512 + n0 + bn;
#pragma unroll
    for (int i = 0; i < 8; ++i) bv[i] = (short)f2bf(p[(size_t)i * 512]);
  };

  loadA(0); loadB(0);
  for (int k0 = 0; k0 < 512; k0 += 32) {
    if (k0) __syncthreads();
    if (t < 128) *(short8*)&As[ar][ac] = av;
    *(short8*)&Bs[bn][bk0] = bv;
    __syncthreads();
    short8 a0 = *(const short8*)&As[wm * 16 + fr][fh];
    short8 b0 = *(const short8*)&Bs[wn * 32 + fr][fh];
    short8 b1 = *(const short8*)&Bs[wn * 32 + 16 + fr][fh];
    if (k0 + 32 < 512) { loadA(k0 + 32); loadB(k0 + 32); }
    acc[0] = __builtin_amdgcn_mfma_f32_16x16x32_bf16(a0, b0, acc[0], 0, 0, 0);
    acc[1] = __builtin_amdgcn_mfma_f32_16x16x32_bf16(a0, b1, acc[1], 0, 0, 0);
  }

  int row0 = m0 + wm * 16 + ((lane >> 4) << 2);
#pragma unroll
  for (int qn = 0; qn < 2; ++qn) {
    int col = n0 + wn * 32 + qn * 16 + (lane & 15);
#pragma unroll
    for (int j = 0; j < 4; ++j) {
      float v = acc[qn][j];
      if (Cadd) v += Cadd[(size_t)(row0 + j) * 512 + col];
      if (do_tanh) {
        float e = __builtin_amdgcn_exp2f(v * TANH_SCALE);
        v = fmaf(-2.0f, __builtin_amdgcn_rcpf(e + 1.0f), 1.0f);
      }
      size_t off = (size_t)(row0 + j) * 512 + col;
      if (OUT_BF) ((u16*)Y)[off] = f2bf(v);
      else ((float*)Y)[off] = v;
    }
  }
}

// mix = attn @ context (batched) -> bf16.  grid (4, 8, 8)
__global__ __launch_bounds__(256) void mix_gemm(
    const float* __restrict__ attn, const float* __restrict__ context,
    u16* __restrict__ mixo) {
  int b = blockIdx.z;
  gemm32_body<false, true>(attn + (size_t)b * TT_DIM * SS,
                           context + (size_t)b * SS * DD, nullptr,
                           mixo + (size_t)b * TT_DIM * DD,
                           blockIdx.x * 32, blockIdx.y * 64, false);
}

// out = tanh(mixo @ out_w[:512] + G).  grid (32, 8)
__global__ __launch_bounds__(256) void final_gemm(
    const u16* __restrict__ mixo, const float* __restrict__ out_w,
    const float* __restrict__ G, float* __restrict__ out) {
  gemm32_body<true, false>(mixo, out_w, G, out,
                           blockIdx.x * 32, blockIdx.y * 64, true);
}

// ---------------------------------------------------------------------------
// Fused logits+softmax, lanes-over-s layout (no per-s reduction).
// logit[t,s] = base - 2*sum_d q_d/(E[t,d]*Ft[b,d,s]+1); attn = softmax_s.
// grid = B*T/4 (256), block = 1024 (16 waves). Wave: 2 t-rows x 64 s, d serial.
// E[t,d], q[d] wave-uniform -> scalar loads. 4 d's share one rcp:
//   sum q_i/x_i = (nA*dB + nB*dA)/(dA*dB), nA = q0*x1+q1*x0, dA = x0*x1.
// ---------------------------------------------------------------------------
__global__ __launch_bounds__(1024) void logits_softmax_kernel(
    const float* __restrict__ E, const float* __restrict__ Ft,
    const float* __restrict__ qw, const float* __restrict__ qb,
    float* __restrict__ attn) {
  int bt0 = blockIdx.x * 4;
  int b = bt0 >> 7;  // T = 128
  int tid = threadIdx.x;
  int lane = tid & 63;
  int wv = __builtin_amdgcn_readfirstlane(tid >> 6);  // 0..15, SGPR
  int th = wv >> 3;        // t-half: rows {2th, 2th+1}
  int sc = wv & 7;         // s-chunk
  int s = sc * 64 + lane;

  float qsum = 0.f;
#pragma unroll
  for (int i = 0; i < 8; ++i) qsum += qw[lane + 64 * i];
#pragma unroll
  for (int off = 32; off > 0; off >>= 1) qsum += __shfl_xor(qsum, off, 64);
  float base = qsum + qb[0];

  const float* Fp = Ft + (size_t)b * 512 * 512 + s;   // Ft[b][d][s]
  const float* E0 = E + (size_t)(bt0 + th * 2) * 512;
  const float* E1 = E0 + 512;

  float acc0 = 0.f, acc1 = 0.f;

  f32x4 f;
#pragma unroll
  for (int j = 0; j < 4; ++j) f[j] = Fp[(size_t)j * 512];

  auto quad = [&](const f32x4& e, const f32x4& fc, const f32x4& q4, float& acc) {
    float x0 = fmaf(e[0], fc[0], 1.f), x1 = fmaf(e[1], fc[1], 1.f);
    float x2 = fmaf(e[2], fc[2], 1.f), x3 = fmaf(e[3], fc[3], 1.f);
    float dA = x0 * x1, dB = x2 * x3;
    float nA = fmaf(q4[0], x1, q4[1] * x0);
    float nB = fmaf(q4[2], x3, q4[3] * x2);
    float N = fmaf(nA, dB, nB * dA);
    acc = fmaf(N, __builtin_amdgcn_rcpf(dA * dB), acc);
  };

  for (int d0 = 0; d0 < 508; d0 += 4) {
    f32x4 fc = f;
#pragma unroll
    for (int j = 0; j < 4; ++j) f[j] = Fp[(size_t)(d0 + 4 + j) * 512];
    f32x4 q4 = *(const f32x4*)(qw + d0);
    f32x4 e0 = *(const f32x4*)(E0 + d0);
    f32x4 e1 = *(const f32x4*)(E1 + d0);
    quad(e0, fc, q4, acc0);
    quad(e1, fc, q4, acc1);
  }
  {
    f32x4 q4 = *(const f32x4*)(qw + 508);
    f32x4 e0 = *(const f32x4*)(E0 + 508);
    f32x4 e1 = *(const f32x4*)(E1 + 508);
    quad(e0, f, q4, acc0);
    quad(e1, f, q4, acc1);
  }

  float l0 = fmaf(-2.f, acc0, base);
  float l1 = fmaf(-2.f, acc1, base);

  __shared__ float rmax[4][8], rsum[4][8];
  float m0 = l0, m1 = l1;
#pragma unroll
  for (int off = 32; off > 0; off >>= 1) {
    m0 = fmaxf(m0, __shfl_xor(m0, off, 64));
    m1 = fmaxf(m1, __shfl_xor(m1, off, 64));
  }
  if (lane == 0) { rmax[th * 2][sc] = m0; rmax[th * 2 + 1][sc] = m1; }
  __syncthreads();
  float M0 = rmax[th * 2][0], M1 = rmax[th * 2 + 1][0];
#pragma unroll
  for (int i = 1; i < 8; ++i) {
    M0 = fmaxf(M0, rmax[th * 2][i]);
    M1 = fmaxf(M1, rmax[th * 2 + 1][i]);
  }
  float ex0 = __builtin_amdgcn_exp2f((l0 - M0) * LOG2E);
  float ex1 = __builtin_amdgcn_exp2f((l1 - M1) * LOG2E);
  float s0v = ex0, s1v = ex1;
#pragma unroll
  for (int off = 32; off > 0; off >>= 1) {
    s0v += __shfl_xor(s0v, off, 64);
    s1v += __shfl_xor(s1v, off, 64);
  }
  if (lane == 0) { rsum[th * 2][sc] = s0v; rsum[th * 2 + 1][sc] = s1v; }
  __syncthreads();
  float S0 = 0.f, S1 = 0.f;
#pragma unroll
  for (int i = 0; i < 8; ++i) { S0 += rsum[th * 2][i]; S1 += rsum[th * 2 + 1][i]; }
  attn[(size_t)(bt0 + th * 2) * 512 + s] = ex0 * __builtin_amdgcn_rcpf(S0);
  attn[(size_t)(bt0 + th * 2 + 1) * 512 + s] = ex1 * __builtin_amdgcn_rcpf(S1);
}

extern "C" void kernel_launch(void* const* d_in, const int* in_sizes, int n_in,
                              void* d_out, int out_size, void* d_ws, size_t ws_size,
                              hipStream_t stream) {
  const float* output  = (const float*)d_in[0];  // [B,T,D]
  const float* context = (const float*)d_in[1];  // [B,S,C]
  const float* dec_w   = (const float*)d_in[2];  // [D,D]
  const float* dec_b   = (const float*)d_in[3];
  const float* attn_w  = (const float*)d_in[4];  // [C,D]
  const float* attn_b  = (const float*)d_in[5];
  const float* qw      = (const float*)d_in[6];  // [D,1]
  const float* qb      = (const float*)d_in[7];  // [1]
  const float* out_w   = (const float*)d_in[8];  // [1024,512]
  const float* out_b   = (const float*)d_in[9];

  float* out_p  = (float*)d_out;                     // [B,T,D]
  float* attn_p = out_p + (size_t)BB * TT_DIM * DD;  // [B,T,S]

  char* p = (char*)d_ws;
  float* E  = (float*)p; p += (size_t)BB * TT_DIM * DD * 4;  // 2MB
  float* Ft = (float*)p; p += (size_t)BB * SS * DD * 4;      // 8MB (transposed)
  float* G  = (float*)p; p += (size_t)BB * TT_DIM * DD * 4;  // 2MB
  u16* mixo = (u16*)p;   p += (size_t)BB * TT_DIM * DD * 2;  // 1MB

  ef_gemm<<<dim3(96, 8), 256, 0, stream>>>(output, dec_w, dec_b, context,
                                           attn_w, attn_b, out_w, out_b,
                                           E, Ft, G);
  logits_softmax_kernel<<<dim3(BB * TT_DIM / 4), 1024, 0, stream>>>(
      E, Ft, qw, qb, attn_p);
  mix_gemm<<<dim3(4, 8, 8), 256, 0, stream>>>(attn_p, context, mixo);
  final_gemm<<<dim3(32, 8), 256, 0, stream>>>(mixo, out_w, G, out_p);
}